// Round 9
// baseline (5967.462 us; speedup 1.0000x reference)
//
#include <hip/hip_runtime.h>
#include <cstdint>
#include <cstddef>

#define N_NODES 100000
#define N_EDGES 1600000
#define IN_DIM 963
#define HID 192
#define OUT_DIM 3

typedef _Float16 f16x8 __attribute__((ext_vector_type(8)));
typedef float f32x4 __attribute__((ext_vector_type(4)));

// ---------------------------------------------------------------------------
// CSR build (deterministic: rows sorted by original edge index)
// ---------------------------------------------------------------------------
__global__ void count_kernel(const int* __restrict__ dst, int* __restrict__ counts, int E) {
    int i = blockIdx.x * blockDim.x + threadIdx.x;
    if (i < E) atomicAdd(&counts[dst[i]], 1);
}

__global__ __launch_bounds__(256)
void scan_local(const int* __restrict__ counts, int* __restrict__ rp,
                int* __restrict__ bsum, int n) {
    __shared__ int sm[256];
    const int base = blockIdx.x * 1024;
    const int t = threadIdx.x;
    const int i0 = base + t * 4;
    int v[4];
#pragma unroll
    for (int j = 0; j < 4; ++j) v[j] = (i0 + j < n) ? counts[i0 + j] : 0;
    v[1] += v[0]; v[2] += v[1]; v[3] += v[2];
    sm[t] = v[3];
    __syncthreads();
    for (int off = 1; off < 256; off <<= 1) {
        int add = (t >= off) ? sm[t - off] : 0;
        __syncthreads();
        sm[t] += add;
        __syncthreads();
    }
    const int pre = (t > 0) ? sm[t - 1] : 0;
#pragma unroll
    for (int j = 0; j < 4; ++j) {
        int idx = i0 + j;
        if (idx < n) rp[idx + 1] = pre + v[j];
    }
    if (t == 255) bsum[blockIdx.x] = sm[255];
}

__global__ __launch_bounds__(128)
void scan_block(int* __restrict__ bsum, int nb) {
    __shared__ int sm[128];
    const int t = threadIdx.x;
    const int v = (t < nb) ? bsum[t] : 0;
    sm[t] = v;
    __syncthreads();
    for (int off = 1; off < 128; off <<= 1) {
        int add = (t >= off) ? sm[t - off] : 0;
        __syncthreads();
        sm[t] += add;
        __syncthreads();
    }
    if (t < nb) bsum[t] = sm[t] - v;   // exclusive block offsets
}

__global__ void scan_add(const int* __restrict__ bsum, int* __restrict__ rp, int n) {
    int i = blockIdx.x * blockDim.x + threadIdx.x;
    if (i < n) rp[i + 1] += bsum[i >> 10];
    if (i == 0) rp[0] = 0;
}

__global__ void copy_cursor_kernel(const int* __restrict__ rp, int* __restrict__ cursor, int n) {
    int i = blockIdx.x * blockDim.x + threadIdx.x;
    if (i < n) cursor[i] = rp[i];
}

__global__ void scatter_kernel(const int* __restrict__ src, const int* __restrict__ dst,
                               const float* __restrict__ w, int* __restrict__ cursor,
                               int* __restrict__ csr_src, float* __restrict__ csr_w,
                               int* __restrict__ csr_eid, int E) {
    int i = blockIdx.x * blockDim.x + threadIdx.x;
    if (i < E) {
        int d = dst[i];
        int p = atomicAdd(&cursor[d], 1);
        csr_src[p] = src[i];
        csr_w[p] = w[i];
        csr_eid[p] = i;
    }
}

__global__ void sortrow_kernel(const int* __restrict__ rp, int* __restrict__ csr_src,
                               float* __restrict__ csr_w, int* __restrict__ csr_eid, int n) {
    int r = blockIdx.x * blockDim.x + threadIdx.x;
    if (r >= n) return;
    int s = rp[r], e = rp[r + 1];
    for (int i = s + 1; i < e; ++i) {
        int ke = csr_eid[i]; int ks = csr_src[i]; float kw = csr_w[i];
        int j = i - 1;
        while (j >= s && csr_eid[j] > ke) {
            csr_eid[j + 1] = csr_eid[j];
            csr_src[j + 1] = csr_src[j];
            csr_w[j + 1] = csr_w[j];
            --j;
        }
        csr_eid[j + 1] = ke; csr_src[j + 1] = ks; csr_w[j + 1] = kw;
    }
}

// ---------------------------------------------------------------------------
// Weight transpose + fp16 hi/lo split
// ---------------------------------------------------------------------------
__global__ __launch_bounds__(256)
void trans_split(const float* __restrict__ W, const float* __restrict__ L,
                 int K, int Kp, _Float16* __restrict__ out_hi, _Float16* __restrict__ out_lo) {
    __shared__ float tile[32][33];
    const int n0 = blockIdx.x * 32, k0 = blockIdx.y * 32;
    const int tx = threadIdx.x, ty = threadIdx.y;   // (32, 8)
#pragma unroll
    for (int i = 0; i < 4; ++i) {
        int k = k0 + ty + i * 8;
        int n = n0 + tx;
        float v = 0.f;
        if (k < K) v = (n < HID) ? W[(size_t)k * HID + n] : L[(size_t)k * HID + (n - HID)];
        tile[ty + i * 8][tx] = v;
    }
    __syncthreads();
#pragma unroll
    for (int i = 0; i < 4; ++i) {
        int nl = ty + i * 8;
        int n = n0 + nl;
        int k = k0 + tx;
        float v = tile[tx][nl];
        _Float16 hi = (_Float16)v;
        _Float16 lo = (_Float16)(v - (float)hi);
        out_hi[(size_t)n * Kp + k] = hi;
        out_lo[(size_t)n * Kp + k] = lo;
    }
}

// ---------------------------------------------------------------------------
// MFMA dual GEMM (fp16x3 split), m97-structure (frozen from R6)
// ---------------------------------------------------------------------------
__global__ __launch_bounds__(256, 2)
void gemm_lds(const float* __restrict__ X, int M, int Kx, int Kp,
              const _Float16* __restrict__ Wth, const _Float16* __restrict__ Wtl,
              const float* __restrict__ bias, const float* __restrict__ res,
              float* __restrict__ Hdst, float* __restrict__ Tdst) {
    __shared__ __align__(16) char smem[81920];   // 2 x 40960

    const int m0 = blockIdx.x * 128;
    const int tid = threadIdx.x;
    const int lane = tid & 63;
    const int wave = tid >> 6;           // 0..3
    const int wr = wave >> 1;            // row half (64 rows)
    const int wc = wave & 1;             // col half (96 cols)
    const int kg = lane >> 4;            // 0..3 (k-group of 8)
    const int bcol = blockIdx.y * 192;   // 0 (H-pass) or 192 (T-pass)

    auto stage = [&](int k0, int cb) {
#pragma unroll
        for (int i = 0; i < 4; ++i) {
            const int id = i * 256 + tid;
            const int row = id >> 3, slot = id & 7;
            int gr = m0 + row; if (gr >= M) gr = 0;
            const int srck = k0 + ((slot ^ (row & 7)) << 2);
            const float* src = X + (size_t)gr * Kx + srck;
            void* dst = (void*)(smem + cb + (i * 256 + wave * 64) * 16);
            __builtin_amdgcn_global_load_lds(
                (const __attribute__((address_space(1))) void*)src,
                (__attribute__((address_space(3))) void*)dst, 16, 0, 0);
        }
#pragma unroll
        for (int i = 0; i < 3; ++i) {
            const int id = i * 256 + tid;
            const int row = id >> 2, slot = id & 3;
            const int srck = k0 + ((slot ^ ((row >> 1) & 3)) << 3);
            const size_t go = (size_t)(bcol + row) * Kp + srck;
            void* dsth = (void*)(smem + cb + 16384 + (i * 256 + wave * 64) * 16);
            void* dstl = (void*)(smem + cb + 28672 + (i * 256 + wave * 64) * 16);
            __builtin_amdgcn_global_load_lds(
                (const __attribute__((address_space(1))) void*)(Wth + go),
                (__attribute__((address_space(3))) void*)dsth, 16, 0, 0);
            __builtin_amdgcn_global_load_lds(
                (const __attribute__((address_space(1))) void*)(Wtl + go),
                (__attribute__((address_space(3))) void*)dstl, 16, 0, 0);
        }
    };

    f32x4 acc[4][6];
#pragma unroll
    for (int i = 0; i < 4; ++i)
#pragma unroll
        for (int j = 0; j < 6; ++j)
            acc[i][j] = f32x4{0.f, 0.f, 0.f, 0.f};

    const int nsteps = (Kx + 31) / 32;

    stage(0, 0);
    __syncthreads();

    for (int s = 0; s < nsteps; ++s) {
        const int cb = (s & 1) * 40960;
        if (s + 1 < nsteps) stage((s + 1) * 32, ((s + 1) & 1) * 40960);

        const char* cur = smem + cb;
        f16x8 fah[4], fal[4];
#pragma unroll
        for (int mi = 0; mi < 4; ++mi) {
            const int row = wr * 64 + mi * 16 + (lane & 15);
            const char* rb = cur + row * 128;
            f32x4 a0 = *(const f32x4*)(rb + ((((2 * kg)     ^ (row & 7))) << 4));
            f32x4 a1 = *(const f32x4*)(rb + ((((2 * kg + 1) ^ (row & 7))) << 4));
            f16x8 hi, lo;
#pragma unroll
            for (int j = 0; j < 4; ++j) {
                float x0 = a0[j], x1 = a1[j];
                _Float16 h0 = (_Float16)x0, h1 = (_Float16)x1;
                hi[j] = h0;     hi[4 + j] = h1;
                lo[j] = (_Float16)(x0 - (float)h0);
                lo[4 + j] = (_Float16)(x1 - (float)h1);
            }
            fah[mi] = hi; fal[mi] = lo;
        }
#pragma unroll
        for (int ni = 0; ni < 6; ++ni) {
            const int idx = wc * 96 + ni * 16 + (lane & 15);
            const int off = 16384 + idx * 64 + ((kg ^ ((idx >> 1) & 3)) << 4);
            const f16x8 fbh = *(const f16x8*)(cur + off);
            const f16x8 fbl = *(const f16x8*)(cur + off + 12288);
#pragma unroll
            for (int mi = 0; mi < 4; ++mi)
                acc[mi][ni] = __builtin_amdgcn_mfma_f32_16x16x32_f16(fah[mi], fbh, acc[mi][ni], 0, 0, 0);
#pragma unroll
            for (int mi = 0; mi < 4; ++mi)
                acc[mi][ni] = __builtin_amdgcn_mfma_f32_16x16x32_f16(fal[mi], fbh, acc[mi][ni], 0, 0, 0);
#pragma unroll
            for (int mi = 0; mi < 4; ++mi)
                acc[mi][ni] = __builtin_amdgcn_mfma_f32_16x16x32_f16(fah[mi], fbl, acc[mi][ni], 0, 0, 0);
        }
        __syncthreads();
    }

    const bool isH = (bcol == 0);
#pragma unroll
    for (int mi = 0; mi < 4; ++mi) {
        const int rbase = m0 + wr * 64 + mi * 16 + ((lane >> 4) << 2);
#pragma unroll
        for (int ni = 0; ni < 6; ++ni) {
            const int gc = wc * 96 + ni * 16 + (lane & 15);   // 0..191
            f32x4 v = acc[mi][ni];
            if (isH) {
#pragma unroll
                for (int j = 0; j < 4; ++j) {
                    const int row = rbase + j;
                    if (row < M) Hdst[(size_t)row * HID + gc] = v[j];
                }
            } else {
                const float bv = bias[gc];
#pragma unroll
                for (int j = 0; j < 4; ++j) {
                    const int row = rbase + j;
                    if (row < M) {
                        float t = v[j] + bv;
                        if (res != nullptr) t += res[(size_t)row * HID + gc];
                        Tdst[(size_t)row * HID + gc] = t;
                    }
                }
            }
        }
    }
}

// ---------------------------------------------------------------------------
// SPMM v4: XCD-feature-partitioned. 6 one-line (32-float) feature chunks,
// statically mapped to XCDs via blockIdx%8 (chunks 0 and 3 get 2 XCDs).
// Wave: lanes 0-31 = edge i, lanes 32-63 = edge i+1; one line per edge.
// Parity partials combined via shfl_xor(32) -> deterministic fixed order.
// ---------------------------------------------------------------------------
__global__ __launch_bounds__(256, 8)
void spmm_kernel(const int* __restrict__ rp, const int* __restrict__ csrc,
                 const float* __restrict__ cw, const float* __restrict__ Hm,
                 float* __restrict__ out, float scale) {
    const int tid = threadIdx.x;
    const int lane = tid & 63;
    const int wid = tid >> 6;            // wave in block, 0..3
    const int b = blockIdx.x;            // 0..2047
    const int g = b & 7;
    // chunk map {0,0,1,2,3,3,4,5}; residues 1 and 5 are the second XCD
    const int c = (g < 2) ? 0 : (g == 2) ? 1 : (g == 3) ? 2
                 : (g < 6) ? 3 : (g == 6) ? 4 : 5;
    const bool dbl = (c == 0 || c == 3);
    const int r = (g == 1 || g == 5) ? 1 : 0;
    const int slot = (b >> 3) * (dbl ? 2 : 1) + r;
    const int S = 256 * (dbl ? 2 : 1) * 4;          // wave-slots in this chunk
    const int ws = slot * 4 + wid;

    const int eh = lane >> 5;            // edge parity 0/1
    const int f = lane & 31;             // feature within chunk
    const int fo = c * 32 + f;

    for (int n = ws; n < N_NODES; n += S) {
        const int s = __builtin_amdgcn_readfirstlane(rp[n]);
        const int e = __builtin_amdgcn_readfirstlane(rp[n + 1]);
        float a = 0.f;
        int i = s;
        for (; i + 7 < e; i += 8) {
            float w[4], x[4];
#pragma unroll
            for (int u = 0; u < 4; ++u) {
                const int ei = i + 2 * u + eh;
                w[u] = cw[ei];
                x[u] = Hm[(size_t)csrc[ei] * HID + fo];
            }
#pragma unroll
            for (int u = 0; u < 4; ++u) a += w[u] * x[u];
        }
        for (; i + 1 < e; i += 2) {
            const int ei = i + eh;
            a += cw[ei] * Hm[(size_t)csrc[ei] * HID + fo];
        }
        if (i < e && eh == 0)
            a += cw[i] * Hm[(size_t)csrc[i] * HID + fo];
        a += __shfl_xor(a, 32, 64);      // combine parities (same feature f)
        if (eh == 0) {
            float* o = out + (size_t)n * HID + c * 32;
            o[f] = scale * (o[f] + a);
        }
    }
}

// ---------------------------------------------------------------------------
// Output layer
// ---------------------------------------------------------------------------
__global__ __launch_bounds__(256)
void out_gemm(const float* __restrict__ X, const float* __restrict__ Wout,
              const float* __restrict__ Lout, const float* __restrict__ bout,
              float* __restrict__ H3, float* __restrict__ T3) {
    __shared__ float Ws[HID * OUT_DIM];
    __shared__ float Ls[HID * OUT_DIM];
    int tid = threadIdx.x;
    for (int i = tid; i < HID * OUT_DIM; i += 256) { Ws[i] = Wout[i]; Ls[i] = Lout[i]; }
    __syncthreads();
    int n = blockIdx.x * 4 + (tid >> 6);
    int lane = tid & 63;
    if (n >= N_NODES) return;
    const float* x = X + (size_t)n * HID;
    float aw[3] = {0.f, 0.f, 0.f}, al[3] = {0.f, 0.f, 0.f};
#pragma unroll
    for (int p = 0; p < 3; ++p) {
        int k = p * 64 + lane;
        float xv = x[k];
#pragma unroll
        for (int c = 0; c < 3; ++c) {
            aw[c] += xv * Ws[k * 3 + c];
            al[c] += xv * Ls[k * 3 + c];
        }
    }
#pragma unroll
    for (int off = 32; off > 0; off >>= 1) {
#pragma unroll
        for (int c = 0; c < 3; ++c) {
            aw[c] += __shfl_down(aw[c], off, 64);
            al[c] += __shfl_down(al[c], off, 64);
        }
    }
    if (lane == 0) {
#pragma unroll
        for (int c = 0; c < 3; ++c) {
            H3[n * 3 + c] = aw[c];
            T3[n * 3 + c] = al[c] + bout[c];
        }
    }
}

__global__ __launch_bounds__(256)
void out_spmm(const int* __restrict__ rp, const int* __restrict__ csrc,
              const float* __restrict__ cw, const float* __restrict__ H3,
              const float* __restrict__ T3, float* __restrict__ out) {
    int n = blockIdx.x * blockDim.x + threadIdx.x;
    if (n >= N_NODES) return;
    int s = rp[n], e = rp[n + 1];
    float a0 = 0.f, a1 = 0.f, a2 = 0.f;
    for (int i = s; i < e; ++i) {
        float w = cw[i];
        int src = csrc[i];
        a0 += w * H3[src * 3 + 0];
        a1 += w * H3[src * 3 + 1];
        a2 += w * H3[src * 3 + 2];
    }
    out[n * 3 + 0] = a0 + T3[n * 3 + 0];
    out[n * 3 + 1] = a1 + T3[n * 3 + 1];
    out[n * 3 + 2] = a2 + T3[n * 3 + 2];
}

// ---------------------------------------------------------------------------
extern "C" void kernel_launch(void* const* d_in, const int* in_sizes, int n_in,
                              void* d_out, int out_size, void* d_ws, size_t ws_size,
                              hipStream_t stream) {
    const float* X0    = (const float*)d_in[0];
    const int*   esrc  = (const int*)d_in[1];
    const int*   edst  = (const int*)d_in[2];
    const float* ew    = (const float*)d_in[3];
    const float* w_in  = (const float*)d_in[4];
    const float* l_in  = (const float*)d_in[5];
    const float* b_in  = (const float*)d_in[6];
    const float* bw    = (const float*)d_in[7];   // [6,2,192,192]
    const float* bl    = (const float*)d_in[8];
    const float* bb    = (const float*)d_in[9];   // [6,2,192]
    const float* w_out = (const float*)d_in[10];
    const float* l_out = (const float*)d_in[11];
    const float* b_out = (const float*)d_in[12];

    char* ws = (char*)d_ws;
    size_t off = 0;
    auto alloc = [&](size_t bytes) -> void* {
        void* p = ws + off;
        off += (bytes + 255) & ~(size_t)255;
        return p;
    };
    float* Hbuf   = (float*)alloc(sizeof(float) * (size_t)N_NODES * HID);
    float* h1     = (float*)alloc(sizeof(float) * (size_t)N_NODES * HID);
    int*   counts = (int*)alloc(sizeof(int) * N_NODES);
    int*   rp     = (int*)alloc(sizeof(int) * (N_NODES + 1));
    int*   cursor = (int*)alloc(sizeof(int) * N_NODES);
    int*   bsum   = (int*)alloc(sizeof(int) * 128);
    int*   csrc   = (int*)alloc(sizeof(int) * N_EDGES);
    float* cw     = (float*)alloc(sizeof(float) * N_EDGES);
    int*   ceid   = (int*)alloc(sizeof(int) * N_EDGES);
    float* H3     = (float*)alloc(sizeof(float) * (size_t)N_NODES * OUT_DIM);
    float* T3     = (float*)alloc(sizeof(float) * (size_t)N_NODES * OUT_DIM);
    const int KP0 = 992;
    _Float16* Wt0h = (_Float16*)alloc(sizeof(_Float16) * 384 * KP0);
    _Float16* Wt0l = (_Float16*)alloc(sizeof(_Float16) * 384 * KP0);
    _Float16* WtHh = (_Float16*)alloc(sizeof(_Float16) * 12 * 384 * HID);
    _Float16* WtHl = (_Float16*)alloc(sizeof(_Float16) * 12 * 384 * HID);

    float* xout = (float*)d_out;                  // [N_NODES, 3]
    float* xcat = (float*)d_out + (size_t)N_NODES * OUT_DIM;  // [N_NODES, 192]

    // --- weight transpose + split (all layers, up front) ---
    trans_split<<<dim3(12, 31), dim3(32, 8), 0, stream>>>(w_in, l_in, IN_DIM, KP0, Wt0h, Wt0l);
    for (int l = 0; l < 12; ++l) {
        trans_split<<<dim3(12, 6), dim3(32, 8), 0, stream>>>(
            bw + (size_t)l * HID * HID, bl + (size_t)l * HID * HID, HID, HID,
            WtHh + (size_t)l * 384 * HID, WtHl + (size_t)l * 384 * HID);
    }

    // --- CSR build (deterministic) ---
    const int NB = (N_NODES + 1023) / 1024;   // 98
    hipMemsetAsync(counts, 0, sizeof(int) * N_NODES, stream);
    count_kernel<<<(N_EDGES + 255) / 256, 256, 0, stream>>>(edst, counts, N_EDGES);
    scan_local<<<NB, 256, 0, stream>>>(counts, rp, bsum, N_NODES);
    scan_block<<<1, 128, 0, stream>>>(bsum, NB);
    scan_add<<<(N_NODES + 255) / 256, 256, 0, stream>>>(bsum, rp, N_NODES);
    copy_cursor_kernel<<<(N_NODES + 255) / 256, 256, 0, stream>>>(rp, cursor, N_NODES);
    scatter_kernel<<<(N_EDGES + 255) / 256, 256, 0, stream>>>(esrc, edst, ew, cursor,
                                                              csrc, cw, ceid, N_EDGES);
    sortrow_kernel<<<(N_NODES + 255) / 256, 256, 0, stream>>>(rp, csrc, cw, ceid, N_NODES);

    const dim3 gemm_grid((N_NODES + 127) / 128, 2);
    const int spmm_blocks = 2048;   // 8192 persistent waves; %8 -> XCD chunks

    // --- layer 0 ---
    gemm_lds<<<gemm_grid, 256, 0, stream>>>(X0, N_NODES, IN_DIM, KP0, Wt0h, Wt0l,
                                            b_in, nullptr, Hbuf, xcat);
    spmm_kernel<<<spmm_blocks, 256, 0, stream>>>(rp, csrc, cw, Hbuf, xcat, 1.0f);

    // --- 6 residual blocks ---
    for (int b = 0; b < 6; ++b) {
        int l0 = b * 2, l1 = b * 2 + 1;
        const float* B0 = bb + (size_t)l0 * HID;
        const float* B1 = bb + (size_t)l1 * HID;

        gemm_lds<<<gemm_grid, 256, 0, stream>>>(xcat, N_NODES, HID, HID,
                                                WtHh + (size_t)l0 * 384 * HID,
                                                WtHl + (size_t)l0 * 384 * HID,
                                                B0, nullptr, Hbuf, h1);
        spmm_kernel<<<spmm_blocks, 256, 0, stream>>>(rp, csrc, cw, Hbuf, h1, 1.0f);
        gemm_lds<<<gemm_grid, 256, 0, stream>>>(h1, N_NODES, HID, HID,
                                                WtHh + (size_t)l1 * 384 * HID,
                                                WtHl + (size_t)l1 * 384 * HID,
                                                B1, xcat, Hbuf, xcat);
        spmm_kernel<<<spmm_blocks, 256, 0, stream>>>(rp, csrc, cw, Hbuf, xcat, 0.5f);
    }

    // --- output layer ---
    out_gemm<<<(N_NODES + 3) / 4, 256, 0, stream>>>(xcat, w_out, l_out, b_out, H3, T3);
    out_spmm<<<(N_NODES + 255) / 256, 256, 0, stream>>>(rp, csrc, cw, H3, T3, xout);
}

// Round 10
// 4627.803 us; speedup vs baseline: 1.2895x; 1.2895x over previous
//
#include <hip/hip_runtime.h>
#include <cstdint>
#include <cstddef>

#define N_NODES 100000
#define N_EDGES 1600000
#define IN_DIM 963
#define HID 192
#define OUT_DIM 3

typedef _Float16 f16x8 __attribute__((ext_vector_type(8)));
typedef float f32x4 __attribute__((ext_vector_type(4)));

// ---------------------------------------------------------------------------
// CSR build (deterministic: rows sorted by original edge index)
// ---------------------------------------------------------------------------
__global__ void count_kernel(const int* __restrict__ dst, int* __restrict__ counts, int E) {
    int i = blockIdx.x * blockDim.x + threadIdx.x;
    if (i < E) atomicAdd(&counts[dst[i]], 1);
}

__global__ __launch_bounds__(256)
void scan_local(const int* __restrict__ counts, int* __restrict__ rp,
                int* __restrict__ bsum, int n) {
    __shared__ int sm[256];
    const int base = blockIdx.x * 1024;
    const int t = threadIdx.x;
    const int i0 = base + t * 4;
    int v[4];
#pragma unroll
    for (int j = 0; j < 4; ++j) v[j] = (i0 + j < n) ? counts[i0 + j] : 0;
    v[1] += v[0]; v[2] += v[1]; v[3] += v[2];
    sm[t] = v[3];
    __syncthreads();
    for (int off = 1; off < 256; off <<= 1) {
        int add = (t >= off) ? sm[t - off] : 0;
        __syncthreads();
        sm[t] += add;
        __syncthreads();
    }
    const int pre = (t > 0) ? sm[t - 1] : 0;
#pragma unroll
    for (int j = 0; j < 4; ++j) {
        int idx = i0 + j;
        if (idx < n) rp[idx + 1] = pre + v[j];
    }
    if (t == 255) bsum[blockIdx.x] = sm[255];
}

__global__ __launch_bounds__(128)
void scan_block(int* __restrict__ bsum, int nb) {
    __shared__ int sm[128];
    const int t = threadIdx.x;
    const int v = (t < nb) ? bsum[t] : 0;
    sm[t] = v;
    __syncthreads();
    for (int off = 1; off < 128; off <<= 1) {
        int add = (t >= off) ? sm[t - off] : 0;
        __syncthreads();
        sm[t] += add;
        __syncthreads();
    }
    if (t < nb) bsum[t] = sm[t] - v;   // exclusive block offsets
}

__global__ void scan_add(const int* __restrict__ bsum, int* __restrict__ rp, int n) {
    int i = blockIdx.x * blockDim.x + threadIdx.x;
    if (i < n) rp[i + 1] += bsum[i >> 10];
    if (i == 0) rp[0] = 0;
}

__global__ void copy_cursor_kernel(const int* __restrict__ rp, int* __restrict__ cursor, int n) {
    int i = blockIdx.x * blockDim.x + threadIdx.x;
    if (i < n) cursor[i] = rp[i];
}

__global__ void scatter_kernel(const int* __restrict__ src, const int* __restrict__ dst,
                               const float* __restrict__ w, int* __restrict__ cursor,
                               int* __restrict__ csr_src, float* __restrict__ csr_w,
                               int* __restrict__ csr_eid, int E) {
    int i = blockIdx.x * blockDim.x + threadIdx.x;
    if (i < E) {
        int d = dst[i];
        int p = atomicAdd(&cursor[d], 1);
        csr_src[p] = src[i];
        csr_w[p] = w[i];
        csr_eid[p] = i;
    }
}

__global__ void sortrow_kernel(const int* __restrict__ rp, int* __restrict__ csr_src,
                               float* __restrict__ csr_w, int* __restrict__ csr_eid, int n) {
    int r = blockIdx.x * blockDim.x + threadIdx.x;
    if (r >= n) return;
    int s = rp[r], e = rp[r + 1];
    for (int i = s + 1; i < e; ++i) {
        int ke = csr_eid[i]; int ks = csr_src[i]; float kw = csr_w[i];
        int j = i - 1;
        while (j >= s && csr_eid[j] > ke) {
            csr_eid[j + 1] = csr_eid[j];
            csr_src[j + 1] = csr_src[j];
            csr_w[j + 1] = csr_w[j];
            --j;
        }
        csr_eid[j + 1] = ke; csr_src[j + 1] = ks; csr_w[j + 1] = kw;
    }
}

// ---------------------------------------------------------------------------
// Weight transpose + fp16 hi/lo split
// ---------------------------------------------------------------------------
__global__ __launch_bounds__(256)
void trans_split(const float* __restrict__ W, const float* __restrict__ L,
                 int K, int Kp, _Float16* __restrict__ out_hi, _Float16* __restrict__ out_lo) {
    __shared__ float tile[32][33];
    const int n0 = blockIdx.x * 32, k0 = blockIdx.y * 32;
    const int tx = threadIdx.x, ty = threadIdx.y;   // (32, 8)
#pragma unroll
    for (int i = 0; i < 4; ++i) {
        int k = k0 + ty + i * 8;
        int n = n0 + tx;
        float v = 0.f;
        if (k < K) v = (n < HID) ? W[(size_t)k * HID + n] : L[(size_t)k * HID + (n - HID)];
        tile[ty + i * 8][tx] = v;
    }
    __syncthreads();
#pragma unroll
    for (int i = 0; i < 4; ++i) {
        int nl = ty + i * 8;
        int n = n0 + nl;
        int k = k0 + tx;
        float v = tile[tx][nl];
        _Float16 hi = (_Float16)v;
        _Float16 lo = (_Float16)(v - (float)hi);
        out_hi[(size_t)n * Kp + k] = hi;
        out_lo[(size_t)n * Kp + k] = lo;
    }
}

// ---------------------------------------------------------------------------
// MFMA dual GEMM (fp16x3 split), m97-structure (frozen from R6)
// ---------------------------------------------------------------------------
__global__ __launch_bounds__(256, 2)
void gemm_lds(const float* __restrict__ X, int M, int Kx, int Kp,
              const _Float16* __restrict__ Wth, const _Float16* __restrict__ Wtl,
              const float* __restrict__ bias, const float* __restrict__ res,
              float* __restrict__ Hdst, float* __restrict__ Tdst) {
    __shared__ __align__(16) char smem[81920];   // 2 x 40960

    const int m0 = blockIdx.x * 128;
    const int tid = threadIdx.x;
    const int lane = tid & 63;
    const int wave = tid >> 6;           // 0..3
    const int wr = wave >> 1;            // row half (64 rows)
    const int wc = wave & 1;             // col half (96 cols)
    const int kg = lane >> 4;            // 0..3 (k-group of 8)
    const int bcol = blockIdx.y * 192;   // 0 (H-pass) or 192 (T-pass)

    auto stage = [&](int k0, int cb) {
#pragma unroll
        for (int i = 0; i < 4; ++i) {
            const int id = i * 256 + tid;
            const int row = id >> 3, slot = id & 7;
            int gr = m0 + row; if (gr >= M) gr = 0;
            const int srck = k0 + ((slot ^ (row & 7)) << 2);
            const float* src = X + (size_t)gr * Kx + srck;
            void* dst = (void*)(smem + cb + (i * 256 + wave * 64) * 16);
            __builtin_amdgcn_global_load_lds(
                (const __attribute__((address_space(1))) void*)src,
                (__attribute__((address_space(3))) void*)dst, 16, 0, 0);
        }
#pragma unroll
        for (int i = 0; i < 3; ++i) {
            const int id = i * 256 + tid;
            const int row = id >> 2, slot = id & 3;
            const int srck = k0 + ((slot ^ ((row >> 1) & 3)) << 3);
            const size_t go = (size_t)(bcol + row) * Kp + srck;
            void* dsth = (void*)(smem + cb + 16384 + (i * 256 + wave * 64) * 16);
            void* dstl = (void*)(smem + cb + 28672 + (i * 256 + wave * 64) * 16);
            __builtin_amdgcn_global_load_lds(
                (const __attribute__((address_space(1))) void*)(Wth + go),
                (__attribute__((address_space(3))) void*)dsth, 16, 0, 0);
            __builtin_amdgcn_global_load_lds(
                (const __attribute__((address_space(1))) void*)(Wtl + go),
                (__attribute__((address_space(3))) void*)dstl, 16, 0, 0);
        }
    };

    f32x4 acc[4][6];
#pragma unroll
    for (int i = 0; i < 4; ++i)
#pragma unroll
        for (int j = 0; j < 6; ++j)
            acc[i][j] = f32x4{0.f, 0.f, 0.f, 0.f};

    const int nsteps = (Kx + 31) / 32;

    stage(0, 0);
    __syncthreads();

    for (int s = 0; s < nsteps; ++s) {
        const int cb = (s & 1) * 40960;
        if (s + 1 < nsteps) stage((s + 1) * 32, ((s + 1) & 1) * 40960);

        const char* cur = smem + cb;
        f16x8 fah[4], fal[4];
#pragma unroll
        for (int mi = 0; mi < 4; ++mi) {
            const int row = wr * 64 + mi * 16 + (lane & 15);
            const char* rb = cur + row * 128;
            f32x4 a0 = *(const f32x4*)(rb + ((((2 * kg)     ^ (row & 7))) << 4));
            f32x4 a1 = *(const f32x4*)(rb + ((((2 * kg + 1) ^ (row & 7))) << 4));
            f16x8 hi, lo;
#pragma unroll
            for (int j = 0; j < 4; ++j) {
                float x0 = a0[j], x1 = a1[j];
                _Float16 h0 = (_Float16)x0, h1 = (_Float16)x1;
                hi[j] = h0;     hi[4 + j] = h1;
                lo[j] = (_Float16)(x0 - (float)h0);
                lo[4 + j] = (_Float16)(x1 - (float)h1);
            }
            fah[mi] = hi; fal[mi] = lo;
        }
#pragma unroll
        for (int ni = 0; ni < 6; ++ni) {
            const int idx = wc * 96 + ni * 16 + (lane & 15);
            const int off = 16384 + idx * 64 + ((kg ^ ((idx >> 1) & 3)) << 4);
            const f16x8 fbh = *(const f16x8*)(cur + off);
            const f16x8 fbl = *(const f16x8*)(cur + off + 12288);
#pragma unroll
            for (int mi = 0; mi < 4; ++mi)
                acc[mi][ni] = __builtin_amdgcn_mfma_f32_16x16x32_f16(fah[mi], fbh, acc[mi][ni], 0, 0, 0);
#pragma unroll
            for (int mi = 0; mi < 4; ++mi)
                acc[mi][ni] = __builtin_amdgcn_mfma_f32_16x16x32_f16(fal[mi], fbh, acc[mi][ni], 0, 0, 0);
#pragma unroll
            for (int mi = 0; mi < 4; ++mi)
                acc[mi][ni] = __builtin_amdgcn_mfma_f32_16x16x32_f16(fah[mi], fbl, acc[mi][ni], 0, 0, 0);
        }
        __syncthreads();
    }

    const bool isH = (bcol == 0);
#pragma unroll
    for (int mi = 0; mi < 4; ++mi) {
        const int rbase = m0 + wr * 64 + mi * 16 + ((lane >> 4) << 2);
#pragma unroll
        for (int ni = 0; ni < 6; ++ni) {
            const int gc = wc * 96 + ni * 16 + (lane & 15);   // 0..191
            f32x4 v = acc[mi][ni];
            if (isH) {
#pragma unroll
                for (int j = 0; j < 4; ++j) {
                    const int row = rbase + j;
                    if (row < M) Hdst[(size_t)row * HID + gc] = v[j];
                }
            } else {
                const float bv = bias[gc];
#pragma unroll
                for (int j = 0; j < 4; ++j) {
                    const int row = rbase + j;
                    if (row < M) {
                        float t = v[j] + bv;
                        if (res != nullptr) t += res[(size_t)row * HID + gc];
                        Tdst[(size_t)row * HID + gc] = t;
                    }
                }
            }
        }
    }
}

// ---------------------------------------------------------------------------
// SPMM (R8 structure, MLP-depth fix): task = (node, 64-feature chunk);
// 1 dword gather per edge per lane, 16-edge unroll; launch_bounds(256,4)
// so the full unroll stays in registers (16 outstanding gathers/wave).
// 1024 persistent blocks = 4096 waves = 16 waves/CU.
// ---------------------------------------------------------------------------
__global__ __launch_bounds__(256, 4)
void spmm_kernel(const int* __restrict__ rp, const int* __restrict__ csrc,
                 const float* __restrict__ cw, const float* __restrict__ Hm,
                 float* __restrict__ out, float scale) {
    const int lane = threadIdx.x & 63;
    const int nwaves = (gridDim.x * blockDim.x) >> 6;
    const int ntasks = N_NODES * 3;
    for (int task = (blockIdx.x * blockDim.x + threadIdx.x) >> 6; task < ntasks;
         task += nwaves) {
        const int wid = task / 3;
        const int ch = task - wid * 3;
        const int s = __builtin_amdgcn_readfirstlane(rp[wid]);
        const int e = __builtin_amdgcn_readfirstlane(rp[wid + 1]);
        const int fo = ch * 64 + lane;
        float a = 0.f;
        int i = s;
        for (; i + 15 < e; i += 16) {
            float w[16], x[16];
#pragma unroll
            for (int u = 0; u < 16; ++u) {
                w[u] = cw[i + u];
                x[u] = Hm[(size_t)csrc[i + u] * HID + fo];
            }
#pragma unroll
            for (int u = 0; u < 16; ++u) a += w[u] * x[u];
        }
        for (; i + 3 < e; i += 4) {
            float w[4], x[4];
#pragma unroll
            for (int u = 0; u < 4; ++u) {
                w[u] = cw[i + u];
                x[u] = Hm[(size_t)csrc[i + u] * HID + fo];
            }
#pragma unroll
            for (int u = 0; u < 4; ++u) a += w[u] * x[u];
        }
        for (; i < e; ++i)
            a += cw[i] * Hm[(size_t)csrc[i] * HID + fo];
        float* o = out + (size_t)wid * HID + ch * 64;
        o[lane] = scale * (o[lane] + a);
    }
}

// ---------------------------------------------------------------------------
// Output layer
// ---------------------------------------------------------------------------
__global__ __launch_bounds__(256)
void out_gemm(const float* __restrict__ X, const float* __restrict__ Wout,
              const float* __restrict__ Lout, const float* __restrict__ bout,
              float* __restrict__ H3, float* __restrict__ T3) {
    __shared__ float Ws[HID * OUT_DIM];
    __shared__ float Ls[HID * OUT_DIM];
    int tid = threadIdx.x;
    for (int i = tid; i < HID * OUT_DIM; i += 256) { Ws[i] = Wout[i]; Ls[i] = Lout[i]; }
    __syncthreads();
    int n = blockIdx.x * 4 + (tid >> 6);
    int lane = tid & 63;
    if (n >= N_NODES) return;
    const float* x = X + (size_t)n * HID;
    float aw[3] = {0.f, 0.f, 0.f}, al[3] = {0.f, 0.f, 0.f};
#pragma unroll
    for (int p = 0; p < 3; ++p) {
        int k = p * 64 + lane;
        float xv = x[k];
#pragma unroll
        for (int c = 0; c < 3; ++c) {
            aw[c] += xv * Ws[k * 3 + c];
            al[c] += xv * Ls[k * 3 + c];
        }
    }
#pragma unroll
    for (int off = 32; off > 0; off >>= 1) {
#pragma unroll
        for (int c = 0; c < 3; ++c) {
            aw[c] += __shfl_down(aw[c], off, 64);
            al[c] += __shfl_down(al[c], off, 64);
        }
    }
    if (lane == 0) {
#pragma unroll
        for (int c = 0; c < 3; ++c) {
            H3[n * 3 + c] = aw[c];
            T3[n * 3 + c] = al[c] + bout[c];
        }
    }
}

__global__ __launch_bounds__(256)
void out_spmm(const int* __restrict__ rp, const int* __restrict__ csrc,
              const float* __restrict__ cw, const float* __restrict__ H3,
              const float* __restrict__ T3, float* __restrict__ out) {
    int n = blockIdx.x * blockDim.x + threadIdx.x;
    if (n >= N_NODES) return;
    int s = rp[n], e = rp[n + 1];
    float a0 = 0.f, a1 = 0.f, a2 = 0.f;
    for (int i = s; i < e; ++i) {
        float w = cw[i];
        int src = csrc[i];
        a0 += w * H3[src * 3 + 0];
        a1 += w * H3[src * 3 + 1];
        a2 += w * H3[src * 3 + 2];
    }
    out[n * 3 + 0] = a0 + T3[n * 3 + 0];
    out[n * 3 + 1] = a1 + T3[n * 3 + 1];
    out[n * 3 + 2] = a2 + T3[n * 3 + 2];
}

// ---------------------------------------------------------------------------
extern "C" void kernel_launch(void* const* d_in, const int* in_sizes, int n_in,
                              void* d_out, int out_size, void* d_ws, size_t ws_size,
                              hipStream_t stream) {
    const float* X0    = (const float*)d_in[0];
    const int*   esrc  = (const int*)d_in[1];
    const int*   edst  = (const int*)d_in[2];
    const float* ew    = (const float*)d_in[3];
    const float* w_in  = (const float*)d_in[4];
    const float* l_in  = (const float*)d_in[5];
    const float* b_in  = (const float*)d_in[6];
    const float* bw    = (const float*)d_in[7];   // [6,2,192,192]
    const float* bl    = (const float*)d_in[8];
    const float* bb    = (const float*)d_in[9];   // [6,2,192]
    const float* w_out = (const float*)d_in[10];
    const float* l_out = (const float*)d_in[11];
    const float* b_out = (const float*)d_in[12];

    char* ws = (char*)d_ws;
    size_t off = 0;
    auto alloc = [&](size_t bytes) -> void* {
        void* p = ws + off;
        off += (bytes + 255) & ~(size_t)255;
        return p;
    };
    float* Hbuf   = (float*)alloc(sizeof(float) * (size_t)N_NODES * HID);
    float* h1     = (float*)alloc(sizeof(float) * (size_t)N_NODES * HID);
    int*   counts = (int*)alloc(sizeof(int) * N_NODES);
    int*   rp     = (int*)alloc(sizeof(int) * (N_NODES + 1));
    int*   cursor = (int*)alloc(sizeof(int) * N_NODES);
    int*   bsum   = (int*)alloc(sizeof(int) * 128);
    int*   csrc   = (int*)alloc(sizeof(int) * N_EDGES);
    float* cw     = (float*)alloc(sizeof(float) * N_EDGES);
    int*   ceid   = (int*)alloc(sizeof(int) * N_EDGES);
    float* H3     = (float*)alloc(sizeof(float) * (size_t)N_NODES * OUT_DIM);
    float* T3     = (float*)alloc(sizeof(float) * (size_t)N_NODES * OUT_DIM);
    const int KP0 = 992;
    _Float16* Wt0h = (_Float16*)alloc(sizeof(_Float16) * 384 * KP0);
    _Float16* Wt0l = (_Float16*)alloc(sizeof(_Float16) * 384 * KP0);
    _Float16* WtHh = (_Float16*)alloc(sizeof(_Float16) * 12 * 384 * HID);
    _Float16* WtHl = (_Float16*)alloc(sizeof(_Float16) * 12 * 384 * HID);

    float* xout = (float*)d_out;                  // [N_NODES, 3]
    float* xcat = (float*)d_out + (size_t)N_NODES * OUT_DIM;  // [N_NODES, 192]

    // --- weight transpose + split (all layers, up front) ---
    trans_split<<<dim3(12, 31), dim3(32, 8), 0, stream>>>(w_in, l_in, IN_DIM, KP0, Wt0h, Wt0l);
    for (int l = 0; l < 12; ++l) {
        trans_split<<<dim3(12, 6), dim3(32, 8), 0, stream>>>(
            bw + (size_t)l * HID * HID, bl + (size_t)l * HID * HID, HID, HID,
            WtHh + (size_t)l * 384 * HID, WtHl + (size_t)l * 384 * HID);
    }

    // --- CSR build (deterministic) ---
    const int NB = (N_NODES + 1023) / 1024;   // 98
    hipMemsetAsync(counts, 0, sizeof(int) * N_NODES, stream);
    count_kernel<<<(N_EDGES + 255) / 256, 256, 0, stream>>>(edst, counts, N_EDGES);
    scan_local<<<NB, 256, 0, stream>>>(counts, rp, bsum, N_NODES);
    scan_block<<<1, 128, 0, stream>>>(bsum, NB);
    scan_add<<<(N_NODES + 255) / 256, 256, 0, stream>>>(bsum, rp, N_NODES);
    copy_cursor_kernel<<<(N_NODES + 255) / 256, 256, 0, stream>>>(rp, cursor, N_NODES);
    scatter_kernel<<<(N_EDGES + 255) / 256, 256, 0, stream>>>(esrc, edst, ew, cursor,
                                                              csrc, cw, ceid, N_EDGES);
    sortrow_kernel<<<(N_NODES + 255) / 256, 256, 0, stream>>>(rp, csrc, cw, ceid, N_NODES);

    const dim3 gemm_grid((N_NODES + 127) / 128, 2);
    const int spmm_blocks = 1024;   // 4096 persistent waves = 16/CU, deep MLP

    // --- layer 0 ---
    gemm_lds<<<gemm_grid, 256, 0, stream>>>(X0, N_NODES, IN_DIM, KP0, Wt0h, Wt0l,
                                            b_in, nullptr, Hbuf, xcat);
    spmm_kernel<<<spmm_blocks, 256, 0, stream>>>(rp, csrc, cw, Hbuf, xcat, 1.0f);

    // --- 6 residual blocks ---
    for (int b = 0; b < 6; ++b) {
        int l0 = b * 2, l1 = b * 2 + 1;
        const float* B0 = bb + (size_t)l0 * HID;
        const float* B1 = bb + (size_t)l1 * HID;

        gemm_lds<<<gemm_grid, 256, 0, stream>>>(xcat, N_NODES, HID, HID,
                                                WtHh + (size_t)l0 * 384 * HID,
                                                WtHl + (size_t)l0 * 384 * HID,
                                                B0, nullptr, Hbuf, h1);
        spmm_kernel<<<spmm_blocks, 256, 0, stream>>>(rp, csrc, cw, Hbuf, h1, 1.0f);
        gemm_lds<<<gemm_grid, 256, 0, stream>>>(h1, N_NODES, HID, HID,
                                                WtHh + (size_t)l1 * 384 * HID,
                                                WtHl + (size_t)l1 * 384 * HID,
                                                B1, xcat, Hbuf, xcat);
        spmm_kernel<<<spmm_blocks, 256, 0, stream>>>(rp, csrc, cw, Hbuf, xcat, 0.5f);
    }

    // --- output layer ---
    out_gemm<<<(N_NODES + 3) / 4, 256, 0, stream>>>(xcat, w_out, l_out, b_out, H3, T3);
    out_spmm<<<(N_NODES + 255) / 256, 256, 0, stream>>>(rp, csrc, cw, H3, T3, xout);
}

// Round 11
// 4540.531 us; speedup vs baseline: 1.3143x; 1.0192x over previous
//
#include <hip/hip_runtime.h>
#include <cstdint>
#include <cstddef>

#define N_NODES 100000
#define N_EDGES 1600000
#define IN_DIM 963
#define HID 192
#define OUT_DIM 3

typedef _Float16 f16x8 __attribute__((ext_vector_type(8)));
typedef float f32x4 __attribute__((ext_vector_type(4)));

// ---------------------------------------------------------------------------
// CSR build (deterministic: rows sorted by original edge index)
// ---------------------------------------------------------------------------
__global__ void count_kernel(const int* __restrict__ dst, int* __restrict__ counts, int E) {
    int i = blockIdx.x * blockDim.x + threadIdx.x;
    if (i < E) atomicAdd(&counts[dst[i]], 1);
}

__global__ __launch_bounds__(256)
void scan_local(const int* __restrict__ counts, int* __restrict__ rp,
                int* __restrict__ bsum, int n) {
    __shared__ int sm[256];
    const int base = blockIdx.x * 1024;
    const int t = threadIdx.x;
    const int i0 = base + t * 4;
    int v[4];
#pragma unroll
    for (int j = 0; j < 4; ++j) v[j] = (i0 + j < n) ? counts[i0 + j] : 0;
    v[1] += v[0]; v[2] += v[1]; v[3] += v[2];
    sm[t] = v[3];
    __syncthreads();
    for (int off = 1; off < 256; off <<= 1) {
        int add = (t >= off) ? sm[t - off] : 0;
        __syncthreads();
        sm[t] += add;
        __syncthreads();
    }
    const int pre = (t > 0) ? sm[t - 1] : 0;
#pragma unroll
    for (int j = 0; j < 4; ++j) {
        int idx = i0 + j;
        if (idx < n) rp[idx + 1] = pre + v[j];
    }
    if (t == 255) bsum[blockIdx.x] = sm[255];
}

__global__ __launch_bounds__(128)
void scan_block(int* __restrict__ bsum, int nb) {
    __shared__ int sm[128];
    const int t = threadIdx.x;
    const int v = (t < nb) ? bsum[t] : 0;
    sm[t] = v;
    __syncthreads();
    for (int off = 1; off < 128; off <<= 1) {
        int add = (t >= off) ? sm[t - off] : 0;
        __syncthreads();
        sm[t] += add;
        __syncthreads();
    }
    if (t < nb) bsum[t] = sm[t] - v;   // exclusive block offsets
}

__global__ void scan_add(const int* __restrict__ bsum, int* __restrict__ rp, int n) {
    int i = blockIdx.x * blockDim.x + threadIdx.x;
    if (i < n) rp[i + 1] += bsum[i >> 10];
    if (i == 0) rp[0] = 0;
}

__global__ void copy_cursor_kernel(const int* __restrict__ rp, int* __restrict__ cursor, int n) {
    int i = blockIdx.x * blockDim.x + threadIdx.x;
    if (i < n) cursor[i] = rp[i];
}

__global__ void scatter_kernel(const int* __restrict__ src, const int* __restrict__ dst,
                               const float* __restrict__ w, int* __restrict__ cursor,
                               int* __restrict__ csr_src, float* __restrict__ csr_w,
                               int* __restrict__ csr_eid, int E) {
    int i = blockIdx.x * blockDim.x + threadIdx.x;
    if (i < E) {
        int d = dst[i];
        int p = atomicAdd(&cursor[d], 1);
        csr_src[p] = src[i];
        csr_w[p] = w[i];
        csr_eid[p] = i;
    }
}

__global__ void sortrow_kernel(const int* __restrict__ rp, int* __restrict__ csr_src,
                               float* __restrict__ csr_w, int* __restrict__ csr_eid, int n) {
    int r = blockIdx.x * blockDim.x + threadIdx.x;
    if (r >= n) return;
    int s = rp[r], e = rp[r + 1];
    for (int i = s + 1; i < e; ++i) {
        int ke = csr_eid[i]; int ks = csr_src[i]; float kw = csr_w[i];
        int j = i - 1;
        while (j >= s && csr_eid[j] > ke) {
            csr_eid[j + 1] = csr_eid[j];
            csr_src[j + 1] = csr_src[j];
            csr_w[j + 1] = csr_w[j];
            --j;
        }
        csr_eid[j + 1] = ke; csr_src[j + 1] = ks; csr_w[j + 1] = kw;
    }
}

// ---------------------------------------------------------------------------
// Weight transpose + fp16 hi/lo split:  W[K][192],L[K][192] -> [384][Kp] f16
// ---------------------------------------------------------------------------
__device__ __forceinline__ void trans_split_body(
        const float* W, const float* L, int K, int Kp,
        _Float16* out_hi, _Float16* out_lo, int bx, int by) {
    __shared__ float tile[32][33];
    const int n0 = bx * 32, k0 = by * 32;
    const int tx = threadIdx.x, ty = threadIdx.y;   // (32, 8)
#pragma unroll
    for (int i = 0; i < 4; ++i) {
        int k = k0 + ty + i * 8;
        int n = n0 + tx;
        float v = 0.f;
        if (k < K) v = (n < HID) ? W[(size_t)k * HID + n] : L[(size_t)k * HID + (n - HID)];
        tile[ty + i * 8][tx] = v;
    }
    __syncthreads();
#pragma unroll
    for (int i = 0; i < 4; ++i) {
        int nl = ty + i * 8;
        int n = n0 + nl;
        int k = k0 + tx;
        float v = tile[tx][nl];
        _Float16 hi = (_Float16)v;
        _Float16 lo = (_Float16)(v - (float)hi);
        out_hi[(size_t)n * Kp + k] = hi;
        out_lo[(size_t)n * Kp + k] = lo;
    }
}

__global__ __launch_bounds__(256)
void trans_split(const float* __restrict__ W, const float* __restrict__ L,
                 int K, int Kp, _Float16* __restrict__ out_hi, _Float16* __restrict__ out_lo) {
    trans_split_body(W, L, K, Kp, out_hi, out_lo, blockIdx.x, blockIdx.y);
}

__global__ __launch_bounds__(256)
void trans_split_all(const float* __restrict__ bw, const float* __restrict__ bl,
                     _Float16* __restrict__ outh, _Float16* __restrict__ outl) {
    const int l = blockIdx.z;
    trans_split_body(bw + (size_t)l * HID * HID, bl + (size_t)l * HID * HID, HID, HID,
                     outh + (size_t)l * 384 * HID, outl + (size_t)l * 384 * HID,
                     blockIdx.x, blockIdx.y);
}

// ---------------------------------------------------------------------------
// MFMA dual GEMM (fp16x3 split), m97-structure (frozen from R6)
// ---------------------------------------------------------------------------
__global__ __launch_bounds__(256, 2)
void gemm_lds(const float* __restrict__ X, int M, int Kx, int Kp,
              const _Float16* __restrict__ Wth, const _Float16* __restrict__ Wtl,
              const float* __restrict__ bias, const float* __restrict__ res,
              float* __restrict__ Hdst, float* __restrict__ Tdst) {
    __shared__ __align__(16) char smem[81920];   // 2 x 40960

    const int m0 = blockIdx.x * 128;
    const int tid = threadIdx.x;
    const int lane = tid & 63;
    const int wave = tid >> 6;           // 0..3
    const int wr = wave >> 1;            // row half (64 rows)
    const int wc = wave & 1;             // col half (96 cols)
    const int kg = lane >> 4;            // 0..3 (k-group of 8)
    const int bcol = blockIdx.y * 192;   // 0 (H-pass) or 192 (T-pass)

    auto stage = [&](int k0, int cb) {
#pragma unroll
        for (int i = 0; i < 4; ++i) {
            const int id = i * 256 + tid;
            const int row = id >> 3, slot = id & 7;
            int gr = m0 + row; if (gr >= M) gr = 0;
            const int srck = k0 + ((slot ^ (row & 7)) << 2);
            const float* src = X + (size_t)gr * Kx + srck;
            void* dst = (void*)(smem + cb + (i * 256 + wave * 64) * 16);
            __builtin_amdgcn_global_load_lds(
                (const __attribute__((address_space(1))) void*)src,
                (__attribute__((address_space(3))) void*)dst, 16, 0, 0);
        }
#pragma unroll
        for (int i = 0; i < 3; ++i) {
            const int id = i * 256 + tid;
            const int row = id >> 2, slot = id & 3;
            const int srck = k0 + ((slot ^ ((row >> 1) & 3)) << 3);
            const size_t go = (size_t)(bcol + row) * Kp + srck;
            void* dsth = (void*)(smem + cb + 16384 + (i * 256 + wave * 64) * 16);
            void* dstl = (void*)(smem + cb + 28672 + (i * 256 + wave * 64) * 16);
            __builtin_amdgcn_global_load_lds(
                (const __attribute__((address_space(1))) void*)(Wth + go),
                (__attribute__((address_space(3))) void*)dsth, 16, 0, 0);
            __builtin_amdgcn_global_load_lds(
                (const __attribute__((address_space(1))) void*)(Wtl + go),
                (__attribute__((address_space(3))) void*)dstl, 16, 0, 0);
        }
    };

    f32x4 acc[4][6];
#pragma unroll
    for (int i = 0; i < 4; ++i)
#pragma unroll
        for (int j = 0; j < 6; ++j)
            acc[i][j] = f32x4{0.f, 0.f, 0.f, 0.f};

    const int nsteps = (Kx + 31) / 32;

    stage(0, 0);
    __syncthreads();

    for (int s = 0; s < nsteps; ++s) {
        const int cb = (s & 1) * 40960;
        if (s + 1 < nsteps) stage((s + 1) * 32, ((s + 1) & 1) * 40960);

        const char* cur = smem + cb;
        f16x8 fah[4], fal[4];
#pragma unroll
        for (int mi = 0; mi < 4; ++mi) {
            const int row = wr * 64 + mi * 16 + (lane & 15);
            const char* rb = cur + row * 128;
            f32x4 a0 = *(const f32x4*)(rb + ((((2 * kg)     ^ (row & 7))) << 4));
            f32x4 a1 = *(const f32x4*)(rb + ((((2 * kg + 1) ^ (row & 7))) << 4));
            f16x8 hi, lo;
#pragma unroll
            for (int j = 0; j < 4; ++j) {
                float x0 = a0[j], x1 = a1[j];
                _Float16 h0 = (_Float16)x0, h1 = (_Float16)x1;
                hi[j] = h0;     hi[4 + j] = h1;
                lo[j] = (_Float16)(x0 - (float)h0);
                lo[4 + j] = (_Float16)(x1 - (float)h1);
            }
            fah[mi] = hi; fal[mi] = lo;
        }
#pragma unroll
        for (int ni = 0; ni < 6; ++ni) {
            const int idx = wc * 96 + ni * 16 + (lane & 15);
            const int off = 16384 + idx * 64 + ((kg ^ ((idx >> 1) & 3)) << 4);
            const f16x8 fbh = *(const f16x8*)(cur + off);
            const f16x8 fbl = *(const f16x8*)(cur + off + 12288);
#pragma unroll
            for (int mi = 0; mi < 4; ++mi)
                acc[mi][ni] = __builtin_amdgcn_mfma_f32_16x16x32_f16(fah[mi], fbh, acc[mi][ni], 0, 0, 0);
#pragma unroll
            for (int mi = 0; mi < 4; ++mi)
                acc[mi][ni] = __builtin_amdgcn_mfma_f32_16x16x32_f16(fal[mi], fbh, acc[mi][ni], 0, 0, 0);
#pragma unroll
            for (int mi = 0; mi < 4; ++mi)
                acc[mi][ni] = __builtin_amdgcn_mfma_f32_16x16x32_f16(fah[mi], fbl, acc[mi][ni], 0, 0, 0);
        }
        __syncthreads();
    }

    const bool isH = (bcol == 0);
#pragma unroll
    for (int mi = 0; mi < 4; ++mi) {
        const int rbase = m0 + wr * 64 + mi * 16 + ((lane >> 4) << 2);
#pragma unroll
        for (int ni = 0; ni < 6; ++ni) {
            const int gc = wc * 96 + ni * 16 + (lane & 15);   // 0..191
            f32x4 v = acc[mi][ni];
            if (isH) {
#pragma unroll
                for (int j = 0; j < 4; ++j) {
                    const int row = rbase + j;
                    if (row < M) Hdst[(size_t)row * HID + gc] = v[j];
                }
            } else {
                const float bv = bias[gc];
#pragma unroll
                for (int j = 0; j < 4; ++j) {
                    const int row = rbase + j;
                    if (row < M) {
                        float t = v[j] + bv;
                        if (res != nullptr) t += res[(size_t)row * HID + gc];
                        Tdst[(size_t)row * HID + gc] = t;
                    }
                }
            }
        }
    }
}

// ---------------------------------------------------------------------------
// SPMM v5 (wide gather): one dwordx4 gather per EDGE. Lanes 0..47 cover the
// full 768B row (16B each); lanes 48..63 alias quad 0 and never store.
// 3x fewer gather instructions than v3 at identical line traffic; summation
// order per feature identical to v3 (ascending edge order) -> bit-identical.
// ---------------------------------------------------------------------------
__global__ __launch_bounds__(256, 4)
void spmm_kernel(const int* __restrict__ rp, const int* __restrict__ csrc,
                 const float* __restrict__ cw, const float* __restrict__ Hm,
                 float* __restrict__ out, float scale) {
    const int lane = threadIdx.x & 63;
    const bool act = lane < 48;
    const int fo = act ? lane * 4 : 0;       // float offset within row
    const int nwaves = (gridDim.x * blockDim.x) >> 6;
    for (int wid = (blockIdx.x * blockDim.x + threadIdx.x) >> 6; wid < N_NODES;
         wid += nwaves) {
        const int s = __builtin_amdgcn_readfirstlane(rp[wid]);
        const int e = __builtin_amdgcn_readfirstlane(rp[wid + 1]);
        f32x4 a = {0.f, 0.f, 0.f, 0.f};
        int i = s;
        for (; i + 7 < e; i += 8) {
            float w[8];
            f32x4 x[8];
#pragma unroll
            for (int u = 0; u < 8; ++u) {
                w[u] = cw[i + u];
                x[u] = *(const f32x4*)(Hm + (size_t)csrc[i + u] * HID + fo);
            }
#pragma unroll
            for (int u = 0; u < 8; ++u) {
                a[0] += w[u] * x[u][0];
                a[1] += w[u] * x[u][1];
                a[2] += w[u] * x[u][2];
                a[3] += w[u] * x[u][3];
            }
        }
        for (; i < e; ++i) {
            const float w = cw[i];
            const f32x4 x = *(const f32x4*)(Hm + (size_t)csrc[i] * HID + fo);
            a[0] += w * x[0];
            a[1] += w * x[1];
            a[2] += w * x[2];
            a[3] += w * x[3];
        }
        if (act) {
            float* o = out + (size_t)wid * HID + fo;
            f32x4 ov = *(const f32x4*)o;
            f32x4 r;
            r[0] = scale * (ov[0] + a[0]);
            r[1] = scale * (ov[1] + a[1]);
            r[2] = scale * (ov[2] + a[2]);
            r[3] = scale * (ov[3] + a[3]);
            *(f32x4*)o = r;
        }
    }
}

// ---------------------------------------------------------------------------
// Output layer
// ---------------------------------------------------------------------------
__global__ __launch_bounds__(256)
void out_gemm(const float* __restrict__ X, const float* __restrict__ Wout,
              const float* __restrict__ Lout, const float* __restrict__ bout,
              float* __restrict__ H3, float* __restrict__ T3) {
    __shared__ float Ws[HID * OUT_DIM];
    __shared__ float Ls[HID * OUT_DIM];
    int tid = threadIdx.x;
    for (int i = tid; i < HID * OUT_DIM; i += 256) { Ws[i] = Wout[i]; Ls[i] = Lout[i]; }
    __syncthreads();
    int n = blockIdx.x * 4 + (tid >> 6);
    int lane = tid & 63;
    if (n >= N_NODES) return;
    const float* x = X + (size_t)n * HID;
    float aw[3] = {0.f, 0.f, 0.f}, al[3] = {0.f, 0.f, 0.f};
#pragma unroll
    for (int p = 0; p < 3; ++p) {
        int k = p * 64 + lane;
        float xv = x[k];
#pragma unroll
        for (int c = 0; c < 3; ++c) {
            aw[c] += xv * Ws[k * 3 + c];
            al[c] += xv * Ls[k * 3 + c];
        }
    }
#pragma unroll
    for (int off = 32; off > 0; off >>= 1) {
#pragma unroll
        for (int c = 0; c < 3; ++c) {
            aw[c] += __shfl_down(aw[c], off, 64);
            al[c] += __shfl_down(al[c], off, 64);
        }
    }
    if (lane == 0) {
#pragma unroll
        for (int c = 0; c < 3; ++c) {
            H3[n * 3 + c] = aw[c];
            T3[n * 3 + c] = al[c] + bout[c];
        }
    }
}

__global__ __launch_bounds__(256)
void out_spmm(const int* __restrict__ rp, const int* __restrict__ csrc,
              const float* __restrict__ cw, const float* __restrict__ H3,
              const float* __restrict__ T3, float* __restrict__ out) {
    int n = blockIdx.x * blockDim.x + threadIdx.x;
    if (n >= N_NODES) return;
    int s = rp[n], e = rp[n + 1];
    float a0 = 0.f, a1 = 0.f, a2 = 0.f;
    for (int i = s; i < e; ++i) {
        float w = cw[i];
        int src = csrc[i];
        a0 += w * H3[src * 3 + 0];
        a1 += w * H3[src * 3 + 1];
        a2 += w * H3[src * 3 + 2];
    }
    out[n * 3 + 0] = a0 + T3[n * 3 + 0];
    out[n * 3 + 1] = a1 + T3[n * 3 + 1];
    out[n * 3 + 2] = a2 + T3[n * 3 + 2];
}

// ---------------------------------------------------------------------------
extern "C" void kernel_launch(void* const* d_in, const int* in_sizes, int n_in,
                              void* d_out, int out_size, void* d_ws, size_t ws_size,
                              hipStream_t stream) {
    const float* X0    = (const float*)d_in[0];
    const int*   esrc  = (const int*)d_in[1];
    const int*   edst  = (const int*)d_in[2];
    const float* ew    = (const float*)d_in[3];
    const float* w_in  = (const float*)d_in[4];
    const float* l_in  = (const float*)d_in[5];
    const float* b_in  = (const float*)d_in[6];
    const float* bw    = (const float*)d_in[7];   // [6,2,192,192]
    const float* bl    = (const float*)d_in[8];
    const float* bb    = (const float*)d_in[9];   // [6,2,192]
    const float* w_out = (const float*)d_in[10];
    const float* l_out = (const float*)d_in[11];
    const float* b_out = (const float*)d_in[12];

    char* ws = (char*)d_ws;
    size_t off = 0;
    auto alloc = [&](size_t bytes) -> void* {
        void* p = ws + off;
        off += (bytes + 255) & ~(size_t)255;
        return p;
    };
    float* Hbuf   = (float*)alloc(sizeof(float) * (size_t)N_NODES * HID);
    float* h1     = (float*)alloc(sizeof(float) * (size_t)N_NODES * HID);
    int*   counts = (int*)alloc(sizeof(int) * N_NODES);
    int*   rp     = (int*)alloc(sizeof(int) * (N_NODES + 1));
    int*   cursor = (int*)alloc(sizeof(int) * N_NODES);
    int*   bsum   = (int*)alloc(sizeof(int) * 128);
    int*   csrc   = (int*)alloc(sizeof(int) * N_EDGES);
    float* cw     = (float*)alloc(sizeof(float) * N_EDGES);
    int*   ceid   = (int*)alloc(sizeof(int) * N_EDGES);
    float* H3     = (float*)alloc(sizeof(float) * (size_t)N_NODES * OUT_DIM);
    float* T3     = (float*)alloc(sizeof(float) * (size_t)N_NODES * OUT_DIM);
    const int KP0 = 992;
    _Float16* Wt0h = (_Float16*)alloc(sizeof(_Float16) * 384 * KP0);
    _Float16* Wt0l = (_Float16*)alloc(sizeof(_Float16) * 384 * KP0);
    _Float16* WtHh = (_Float16*)alloc(sizeof(_Float16) * 12 * 384 * HID);
    _Float16* WtHl = (_Float16*)alloc(sizeof(_Float16) * 12 * 384 * HID);

    float* xout = (float*)d_out;                  // [N_NODES, 3]
    float* xcat = (float*)d_out + (size_t)N_NODES * OUT_DIM;  // [N_NODES, 192]

    // --- weight transpose + split (all layers, up front) ---
    trans_split<<<dim3(12, 31), dim3(32, 8), 0, stream>>>(w_in, l_in, IN_DIM, KP0, Wt0h, Wt0l);
    trans_split_all<<<dim3(12, 6, 12), dim3(32, 8), 0, stream>>>(bw, bl, WtHh, WtHl);

    // --- CSR build (deterministic) ---
    const int NB = (N_NODES + 1023) / 1024;   // 98
    hipMemsetAsync(counts, 0, sizeof(int) * N_NODES, stream);
    count_kernel<<<(N_EDGES + 255) / 256, 256, 0, stream>>>(edst, counts, N_EDGES);
    scan_local<<<NB, 256, 0, stream>>>(counts, rp, bsum, N_NODES);
    scan_block<<<1, 128, 0, stream>>>(bsum, NB);
    scan_add<<<(N_NODES + 255) / 256, 256, 0, stream>>>(bsum, rp, N_NODES);
    copy_cursor_kernel<<<(N_NODES + 255) / 256, 256, 0, stream>>>(rp, cursor, N_NODES);
    scatter_kernel<<<(N_EDGES + 255) / 256, 256, 0, stream>>>(esrc, edst, ew, cursor,
                                                              csrc, cw, ceid, N_EDGES);
    sortrow_kernel<<<(N_NODES + 255) / 256, 256, 0, stream>>>(rp, csrc, cw, ceid, N_NODES);

    const dim3 gemm_grid((N_NODES + 127) / 128, 2);
    const int spmm_blocks = 2048;   // 8192 persistent waves

    // --- layer 0 ---
    gemm_lds<<<gemm_grid, 256, 0, stream>>>(X0, N_NODES, IN_DIM, KP0, Wt0h, Wt0l,
                                            b_in, nullptr, Hbuf, xcat);
    spmm_kernel<<<spmm_blocks, 256, 0, stream>>>(rp, csrc, cw, Hbuf, xcat, 1.0f);

    // --- 6 residual blocks ---
    for (int b = 0; b < 6; ++b) {
        int l0 = b * 2, l1 = b * 2 + 1;
        const float* B0 = bb + (size_t)l0 * HID;
        const float* B1 = bb + (size_t)l1 * HID;

        gemm_lds<<<gemm_grid, 256, 0, stream>>>(xcat, N_NODES, HID, HID,
                                                WtHh + (size_t)l0 * 384 * HID,
                                                WtHl + (size_t)l0 * 384 * HID,
                                                B0, nullptr, Hbuf, h1);
        spmm_kernel<<<spmm_blocks, 256, 0, stream>>>(rp, csrc, cw, Hbuf, h1, 1.0f);
        gemm_lds<<<gemm_grid, 256, 0, stream>>>(h1, N_NODES, HID, HID,
                                                WtHh + (size_t)l1 * 384 * HID,
                                                WtHl + (size_t)l1 * 384 * HID,
                                                B1, xcat, Hbuf, xcat);
        spmm_kernel<<<spmm_blocks, 256, 0, stream>>>(rp, csrc, cw, Hbuf, xcat, 0.5f);
    }

    // --- output layer ---
    out_gemm<<<(N_NODES + 3) / 4, 256, 0, stream>>>(xcat, w_out, l_out, b_out, H3, T3);
    out_spmm<<<(N_NODES + 255) / 256, 256, 0, stream>>>(rp, csrc, cw, H3, T3, xout);
}